// Round 16
// baseline (4676.430 us; speedup 1.0000x reference)
//
#include <hip/hip_runtime.h>

#define BATCH 128
#define SEQ   1024
#define INSZ  128
#define HID   256
#define NBLK  32
#define NTHR  512
#define FPB   8            // features per block
#define EPSV  1e-5f

typedef __attribute__((ext_vector_type(4))) float f32x4;
typedef __attribute__((ext_vector_type(8))) short short8;
typedef __attribute__((ext_vector_type(4))) unsigned u32x4;   // asm-safe 16B vector
typedef unsigned u32;

__device__ __forceinline__ unsigned short f2bf(float f) {
  unsigned u = __builtin_bit_cast(unsigned, f);
  u += 0x7FFFu + ((u >> 16) & 1u);          // round-to-nearest-even
  return (unsigned short)(u >> 16);
}
// hardware packed f32->bf16 (RNE)
__device__ __forceinline__ short8 xcvt(float4 f0, float4 f1) {
  u32 a, b, c, d2;
  asm("v_cvt_pk_bf16_f32 %0, %1, %2" : "=v"(a)  : "v"(f0.x), "v"(f0.y));
  asm("v_cvt_pk_bf16_f32 %0, %1, %2" : "=v"(b)  : "v"(f0.z), "v"(f0.w));
  asm("v_cvt_pk_bf16_f32 %0, %1, %2" : "=v"(c)  : "v"(f1.x), "v"(f1.y));
  asm("v_cvt_pk_bf16_f32 %0, %1, %2" : "=v"(d2) : "v"(f1.z), "v"(f1.w));
  u32x4 t = {a, b, c, d2};
  return __builtin_bit_cast(short8, t);
}

__launch_bounds__(NTHR)
__global__ void bnlstm_kernel(const float* __restrict__ x,
                              const float* __restrict__ W,
                              const float* __restrict__ gamma,
                              const float* __restrict__ beta,
                              float* __restrict__ out,
                              unsigned short* __restrict__ hbuf) { // [2][32 slab][128 row][8] bf16
  __shared__ __attribute__((aligned(16))) unsigned short Zs[32 * 1024];     // 64 KB
  __shared__ float red1[2][8][32];                 // parity-buffered BN partials
  __shared__ float red2[2][8][32];
  __shared__ float waveTr[8][16][17];              // per-wave gate transpose
  __shared__ __attribute__((aligned(16))) unsigned short hpack[8][16][8];   // packed h rows

  const int tid   = threadIdx.x;
  const int bid   = blockIdx.x;
  const int lane  = tid & 63;
  const int wid   = tid >> 6;                      // wave w owns batch rows 16w..16w+15
  const int col16 = lane & 15;
  const int kg    = lane >> 4;
  const int d     = col16 & 3;
  const int q     = col16 >> 2;
  const int arow  = wid * 16 + col16;              // A-frag row (batch index)
  const int brow  = wid * 16 + kg * 4 + d;         // gate/output row (batch index)

  // ---- B fragments in registers: 32 cols = (j_local 0..7) x (gate 0..3) ----
  short8 wf[2][12];
  for (int cg = 0; cg < 2; ++cg) {
    const int c32 = cg * 16 + col16;
    const int wcol = (c32 & 3) * HID + bid * FPB + (c32 >> 2);
    for (int kt = 0; kt < 12; ++kt) {
      short8 v;
      for (int e = 0; e < 8; ++e)
        v[e] = (short)f2bf(W[(kt * 32 + kg * 8 + e) * 1024 + wcol]);
      wf[cg][kt] = v;
    }
  }
  float gam = 0.f, bet = 0.f;
  if (lane < 32) {
    gam = gamma[(lane & 3) * HID + bid * FPB + (lane >> 2)];
    bet = beta [(lane & 3) * HID + bid * FPB + (lane >> 2)];
  }
  // bias input skipped: BN subtracts the batch mean, cancelling it exactly.

  float cst[2] = {0.f, 0.f};
  float hnv[2];

  // x(t) f32 loads in flight; converted at the top of step t (static indices only)
  const float* xbase = x + (size_t)arow * (SEQ * INSZ) + kg * 8;
  float4 xv[8];
  #pragma unroll
  for (int kt = 0; kt < 4; ++kt) {
    xv[2 * kt]     = *(const float4*)(xbase + kt * 32);
    xv[2 * kt + 1] = *(const float4*)(xbase + kt * 32 + 4);
  }

  for (int t = 0; t < SEQ; ++t) {
    const int pR = t & 1;
    f32x4 acc0 = {0.f, 0.f, 0.f, 0.f}, acc1 = {0.f, 0.f, 0.f, 0.f};

    // ---- top: convert + x-part MFMAs ----
    #pragma unroll
    for (int kt = 0; kt < 4; ++kt) {
      short8 ax = xcvt(xv[2 * kt], xv[2 * kt + 1]);
      acc0 = __builtin_amdgcn_mfma_f32_16x16x32_bf16(ax, wf[0][kt], acc0, 0, 0, 0);
      acc1 = __builtin_amdgcn_mfma_f32_16x16x32_bf16(ax, wf[1][kt], acc1, 0, 0, 0);
    }
    // ---- reissue x(t+1) ----
    if (t + 1 < SEQ) {
      const float* xr = xbase + (size_t)(t + 1) * INSZ;
      #pragma unroll
      for (int kt = 0; kt < 4; ++kt) {
        xv[2 * kt]     = *(const float4*)(xr + kt * 32);
        xv[2 * kt + 1] = *(const float4*)(xr + kt * 32 + 4);
      }
    }

    if (t > 0) {
      // ---- ONE-HOP stage: poll the tagged data itself (tag = bf16 LSBs).
      // TB(t) = ((t>>1)&0x7f)|0x80: distinguishes generations t vs t-2, and
      // memset-0 can never match. Each bf16 carries its own tag bit -> torn-safe.
      const u32 TB = ((u32)(t >> 1) & 0x7fu) | 0x80u;
      const u32 e0 = ((TB >> 0) & 1u) | (((TB >> 1) & 1u) << 16);
      const u32 e1 = ((TB >> 2) & 1u) | (((TB >> 3) & 1u) << 16);
      const u32 e2 = ((TB >> 4) & 1u) | (((TB >> 5) & 1u) << 16);
      const u32 e3 = ((TB >> 6) & 1u) | (((TB >> 7) & 1u) << 16);
      const unsigned short* hsrc = hbuf + pR * (BATCH * HID);
      u32x4 hvv[8];
      while (true) {
        #pragma unroll
        for (int k = 0; k < 8; ++k) {
          const unsigned short* ap = hsrc + ((k * 4 + kg) * 128 + arow) * 8;
          asm volatile("global_load_dwordx4 %0, %1, off sc0 sc1"
                       : "=v"(hvv[k]) : "v"(ap));
        }
        asm volatile("s_waitcnt vmcnt(0)" ::: "memory");
        u32 bad = 0;
        #pragma unroll
        for (int k = 0; k < 8; ++k) {
          bad |= (hvv[k].x ^ e0) & 0x00010001u;
          bad |= (hvv[k].y ^ e1) & 0x00010001u;
          bad |= (hvv[k].z ^ e2) & 0x00010001u;
          bad |= (hvv[k].w ^ e3) & 0x00010001u;
        }
        if (__all(bad == 0)) break;
        __builtin_amdgcn_s_sleep(2);
      }
      __builtin_amdgcn_sched_barrier(0);           // rule #18: MFMAs stay below
      #pragma unroll
      for (int k = 0; k < 8; ++k)
        *(u32x4*)&Zs[((k * 4 + kg) * 128 + arow) * 8] = hvv[k];
      // NO barrier: wave w reads exactly the rows wave w just wrote

      // ---- h-part MFMAs from LDS ----
      #pragma unroll
      for (int kt = 0; kt < 8; ++kt) {
        short8 af = *(const short8*)&Zs[((kt * 4 + kg) * 128 + arow) * 8];
        acc0 = __builtin_amdgcn_mfma_f32_16x16x32_bf16(af, wf[0][4 + kt], acc0, 0, 0, 0);
        acc1 = __builtin_amdgcn_mfma_f32_16x16x32_bf16(af, wf[1][4 + kt], acc1, 0, 0, 0);
      }
    }

    // ---- BN partials + the ONE block-wide barrier per step ----
    {
      float a1 = acc0[0] + acc0[1] + acc0[2] + acc0[3];
      float b1 = acc0[0]*acc0[0] + acc0[1]*acc0[1] + acc0[2]*acc0[2] + acc0[3]*acc0[3];
      float a2 = acc1[0] + acc1[1] + acc1[2] + acc1[3];
      float b2 = acc1[0]*acc1[0] + acc1[1]*acc1[1] + acc1[2]*acc1[2] + acc1[3]*acc1[3];
      a1 += __shfl_xor(a1, 16); b1 += __shfl_xor(b1, 16);
      a1 += __shfl_xor(a1, 32); b1 += __shfl_xor(b1, 32);
      a2 += __shfl_xor(a2, 16); b2 += __shfl_xor(b2, 16);
      a2 += __shfl_xor(a2, 32); b2 += __shfl_xor(b2, 32);
      if (lane < 16) {
        red1[pR][wid][lane] = a1;       red2[pR][wid][lane] = b1;
        red1[pR][wid][16 + lane] = a2;  red2[pR][wid][16 + lane] = b2;
      }
    }
    __syncthreads();                               // s2: partials visible (parity-buffered)

    // ---- BN finalize: redundant per wave ----
    float sc0v, sh0v, sc1v, sh1v;
    {
      const int cidx = lane & 31;
      float S1 = 0.f, S2 = 0.f;
      #pragma unroll
      for (int w2 = 0; w2 < 8; ++w2) { S1 += red1[pR][w2][cidx]; S2 += red2[pR][w2][cidx]; }
      float mean = S1 * (1.f / BATCH);
      float var  = fmaxf(S2 * (1.f / BATCH) - mean * mean, 0.f);
      float scl = rsqrtf(var + EPSV) * gam;
      float shl = bet - mean * scl;
      sc0v = __shfl(scl, col16);       sh0v = __shfl(shl, col16);
      sc1v = __shfl(scl, 16 + col16);  sh1v = __shfl(shl, 16 + col16);
    }

    // ---- normalize + in-wave transpose + gates; pack TAGGED h rows ----
    const u32 TBn = ((u32)((t + 1) >> 1) & 0x7fu) | 0x80u;   // tag for consumption at t+1
    #pragma unroll
    for (int cg = 0; cg < 2; ++cg) {
      f32x4 a = cg ? acc1 : acc0;
      const float sc = cg ? sc1v : sc0v, sh = cg ? sh1v : sh0v;
      #pragma unroll
      for (int i = 0; i < 4; ++i)
        waveTr[wid][kg * 4 + i][col16] = a[i] * sc + sh;
      float g0 = waveTr[wid][kg * 4 + d][q * 4 + 0];
      float g1 = waveTr[wid][kg * 4 + d][q * 4 + 1];
      float g2 = waveTr[wid][kg * 4 + d][q * 4 + 2];
      float g3 = waveTr[wid][kg * 4 + d][q * 4 + 3];
      float ig = __builtin_amdgcn_rcpf(1.f + __expf(-g0));
      float fg = __builtin_amdgcn_rcpf(1.f + __expf(-g1));
      float gg = 1.f - 2.f * __builtin_amdgcn_rcpf(__expf(2.f * g2) + 1.f);
      float og = __builtin_amdgcn_rcpf(1.f + __expf(-g3));
      float cn = fg * cst[cg] + ig * gg;
      float hn = og * (1.f - 2.f * __builtin_amdgcn_rcpf(__expf(2.f * cn) + 1.f));
      cst[cg] = cn;
      hnv[cg] = hn;
      const int jl = cg * 4 + q;
      hpack[wid][kg * 4 + d][jl] =
          (unsigned short)((f2bf(hn) & 0xFFFEu) | ((TBn >> jl) & 1u));
    }

    if (t < SEQ - 1) {
      // ---- per-wave publish: fire-and-forget (tag travels with the data) ----
      if (lane < 16) {
        u32x4 hv = *(const u32x4*)&hpack[wid][lane][0];
        unsigned short* hd = hbuf + (pR ^ 1) * (BATCH * HID)
                           + (bid * 128 + wid * 16 + lane) * 8;
        asm volatile("global_store_dwordx4 %0, %1, off sc0 sc1"
                     :: "v"(hd), "v"(hv) : "memory");
      }
      // out stores + x issue follow; no ack, no flag, no barrier
      float* po = &out[(size_t)brow * (SEQ * HID) + (size_t)t * HID + bid * FPB];
      po[q]     = hnv[0];
      po[4 + q] = hnv[1];
    } else {
      float* po = &out[(size_t)brow * (SEQ * HID) + (size_t)t * HID + bid * FPB];
      po[q]     = hnv[0];
      po[4 + q] = hnv[1];
      float* ph = &out[(size_t)BATCH * SEQ * HID + (size_t)brow * HID + bid * FPB];
      ph[q] = hnv[0];                 ph[4 + q] = hnv[1];                // hy
      ph[BATCH * HID + q] = cst[0];   ph[BATCH * HID + 4 + q] = cst[1];  // cy
    }
  }
}

extern "C" void kernel_launch(void* const* d_in, const int* in_sizes, int n_in,
                              void* d_out, int out_size, void* d_ws, size_t ws_size,
                              hipStream_t stream) {
  const float* x     = (const float*)d_in[0];
  const float* W     = (const float*)d_in[1];
  // d_in[2] = bias: cancelled by BatchNorm, unused.
  const float* gamma = (const float*)d_in[3];
  const float* beta  = (const float*)d_in[4];
  float* out = (float*)d_out;

  unsigned short* hbuf = (unsigned short*)d_ws;    // 2 x 64 KB tagged h

  // zero the WHOLE hbuf each call: tag byte has bit7 set, so 0 never matches ->
  // kills cross-replay stale-tag collisions
  (void)hipMemsetAsync(d_ws, 0, 2 * BATCH * HID * sizeof(unsigned short), stream);
  hipLaunchKernelGGL(bnlstm_kernel, dim3(NBLK), dim3(NTHR), 0, stream,
                     x, W, gamma, beta, out, hbuf);
}

// Round 17
// 4634.436 us; speedup vs baseline: 1.0091x; 1.0091x over previous
//
#include <hip/hip_runtime.h>

#define BATCH 128
#define SEQ   1024
#define INSZ  128
#define HID   256
#define NBLK  32
#define NTHR  512
#define FPB   8            // features per block
#define EPSV  1e-5f

typedef __attribute__((ext_vector_type(4))) float f32x4;
typedef __attribute__((ext_vector_type(8))) short short8;
typedef __attribute__((ext_vector_type(4))) unsigned u32x4;   // asm-safe 16B vector
typedef unsigned u32;

__device__ __forceinline__ unsigned short f2bf(float f) {
  unsigned u = __builtin_bit_cast(unsigned, f);
  u += 0x7FFFu + ((u >> 16) & 1u);          // round-to-nearest-even
  return (unsigned short)(u >> 16);
}
// hardware packed f32->bf16 (RNE)
__device__ __forceinline__ short8 xcvt(float4 f0, float4 f1) {
  u32 a, b, c, d2;
  asm("v_cvt_pk_bf16_f32 %0, %1, %2" : "=v"(a)  : "v"(f0.x), "v"(f0.y));
  asm("v_cvt_pk_bf16_f32 %0, %1, %2" : "=v"(b)  : "v"(f0.z), "v"(f0.w));
  asm("v_cvt_pk_bf16_f32 %0, %1, %2" : "=v"(c)  : "v"(f1.x), "v"(f1.y));
  asm("v_cvt_pk_bf16_f32 %0, %1, %2" : "=v"(d2) : "v"(f1.z), "v"(f1.w));
  u32x4 t = {a, b, c, d2};
  return __builtin_bit_cast(short8, t);
}

__launch_bounds__(NTHR)
__global__ void bnlstm_kernel(const float* __restrict__ x,
                              const float* __restrict__ W,
                              const float* __restrict__ gamma,
                              const float* __restrict__ beta,
                              float* __restrict__ out,
                              unsigned short* __restrict__ hbuf,   // [2][32 slab][128 row][8] bf16
                              u32* __restrict__ flags) {           // [32 blk][8 wave] @128B
  __shared__ float red1[2][8][32];                 // parity-buffered BN partials
  __shared__ float red2[2][8][32];
  __shared__ float waveTr[8][16][17];              // per-wave gate transpose
  __shared__ __attribute__((aligned(16))) unsigned short hpack[8][16][8];   // packed h rows

  const int tid   = threadIdx.x;
  const int bid   = blockIdx.x;
  const int lane  = tid & 63;
  const int wid   = tid >> 6;                      // wave w owns batch rows 16w..16w+15
  const int col16 = lane & 15;
  const int kg    = lane >> 4;
  const int d     = col16 & 3;
  const int q     = col16 >> 2;
  const int arow  = wid * 16 + col16;              // A-frag row (batch index)
  const int brow  = wid * 16 + kg * 4 + d;         // gate/output row (batch index)

  // ---- B fragments in registers: 32 cols = (j_local 0..7) x (gate 0..3) ----
  short8 wf[2][12];
  for (int cg = 0; cg < 2; ++cg) {
    const int c32 = cg * 16 + col16;
    const int wcol = (c32 & 3) * HID + bid * FPB + (c32 >> 2);
    for (int kt = 0; kt < 12; ++kt) {
      short8 v;
      for (int e = 0; e < 8; ++e)
        v[e] = (short)f2bf(W[(kt * 32 + kg * 8 + e) * 1024 + wcol]);
      wf[cg][kt] = v;
    }
  }
  float gam = 0.f, bet = 0.f;
  if (lane < 32) {
    gam = gamma[(lane & 3) * HID + bid * FPB + (lane >> 2)];
    bet = beta [(lane & 3) * HID + bid * FPB + (lane >> 2)];
  }
  // bias input skipped: BN subtracts the batch mean, cancelling it exactly.

  float cst[2] = {0.f, 0.f};
  float hnv[2];

  // x(t) f32 loads in flight; converted at the top of step t (static indices only)
  const float* xbase = x + (size_t)arow * (SEQ * INSZ) + kg * 8;
  float4 xv[8];
  #pragma unroll
  for (int kt = 0; kt < 4; ++kt) {
    xv[2 * kt]     = *(const float4*)(xbase + kt * 32);
    xv[2 * kt + 1] = *(const float4*)(xbase + kt * 32 + 4);
  }

  for (int t = 0; t < SEQ; ++t) {
    const int pR = t & 1;
    f32x4 acc0 = {0.f, 0.f, 0.f, 0.f}, acc1 = {0.f, 0.f, 0.f, 0.f};

    // ---- top: convert + x-part MFMAs ----
    #pragma unroll
    for (int kt = 0; kt < 4; ++kt) {
      short8 ax = xcvt(xv[2 * kt], xv[2 * kt + 1]);
      acc0 = __builtin_amdgcn_mfma_f32_16x16x32_bf16(ax, wf[0][kt], acc0, 0, 0, 0);
      acc1 = __builtin_amdgcn_mfma_f32_16x16x32_bf16(ax, wf[1][kt], acc1, 0, 0, 0);
    }
    // ---- reissue x(t+1): its latency is absorbed by the poll + stage window ----
    if (t + 1 < SEQ) {
      const float* xr = xbase + (size_t)(t + 1) * INSZ;
      #pragma unroll
      for (int kt = 0; kt < 4; ++kt) {
        xv[2 * kt]     = *(const float4*)(xr + kt * 32);
        xv[2 * kt + 1] = *(const float4*)(xr + kt * 32 + 4);
      }
    }

    if (t > 0) {
      // ---- per-wave detect: wave w polls ONLY the 32 same-w producer flags ----
      {
        const u32 tv = (u32)t;
        while (true) {
          u32 v = (lane < NBLK)
            ? __hip_atomic_load(&flags[(lane * 8 + wid) * 32], __ATOMIC_RELAXED,
                                __HIP_MEMORY_SCOPE_AGENT)
            : tv;
          if (__all((int)(v >= tv))) break;
          __builtin_amdgcn_s_sleep(1);
        }
      }
      // ---- per-wave stage: rows 16w..16w+15 from all 32 slabs, straight to regs.
      // (Load pattern == MFMA A-frag layout; no LDS round trip needed.) ----
      const unsigned short* hsrc = hbuf + pR * (BATCH * HID);
      u32x4 hvv[8];
      #pragma unroll
      for (int k = 0; k < 8; ++k) {
        const unsigned short* ap = hsrc + ((k * 4 + kg) * 128 + arow) * 8;
        asm volatile("global_load_dwordx4 %0, %1, off sc0 sc1"
                     : "=v"(hvv[k]) : "v"(ap));
      }
      asm volatile("s_waitcnt vmcnt(0)" ::: "memory");
      __builtin_amdgcn_sched_barrier(0);           // rule #18: MFMAs stay below the wait

      // ---- h-part MFMAs directly from the staged registers ----
      #pragma unroll
      for (int kt = 0; kt < 8; ++kt) {
        short8 af = __builtin_bit_cast(short8, hvv[kt]);
        acc0 = __builtin_amdgcn_mfma_f32_16x16x32_bf16(af, wf[0][4 + kt], acc0, 0, 0, 0);
        acc1 = __builtin_amdgcn_mfma_f32_16x16x32_bf16(af, wf[1][4 + kt], acc1, 0, 0, 0);
      }
    }

    // ---- BN partials + the ONE block-wide barrier per step ----
    {
      float a1 = acc0[0] + acc0[1] + acc0[2] + acc0[3];
      float b1 = acc0[0]*acc0[0] + acc0[1]*acc0[1] + acc0[2]*acc0[2] + acc0[3]*acc0[3];
      float a2 = acc1[0] + acc1[1] + acc1[2] + acc1[3];
      float b2 = acc1[0]*acc1[0] + acc1[1]*acc1[1] + acc1[2]*acc1[2] + acc1[3]*acc1[3];
      a1 += __shfl_xor(a1, 16); b1 += __shfl_xor(b1, 16);
      a1 += __shfl_xor(a1, 32); b1 += __shfl_xor(b1, 32);
      a2 += __shfl_xor(a2, 16); b2 += __shfl_xor(b2, 16);
      a2 += __shfl_xor(a2, 32); b2 += __shfl_xor(b2, 32);
      if (lane < 16) {
        red1[pR][wid][lane] = a1;       red2[pR][wid][lane] = b1;
        red1[pR][wid][16 + lane] = a2;  red2[pR][wid][16 + lane] = b2;
      }
    }
    __syncthreads();                               // s2: partials visible (parity-buffered)

    // ---- BN finalize: redundant per wave ----
    float sc0v, sh0v, sc1v, sh1v;
    {
      const int cidx = lane & 31;
      float S1 = 0.f, S2 = 0.f;
      #pragma unroll
      for (int w2 = 0; w2 < 8; ++w2) { S1 += red1[pR][w2][cidx]; S2 += red2[pR][w2][cidx]; }
      float mean = S1 * (1.f / BATCH);
      float var  = fmaxf(S2 * (1.f / BATCH) - mean * mean, 0.f);
      float scl = rsqrtf(var + EPSV) * gam;
      float shl = bet - mean * scl;
      sc0v = __shfl(scl, col16);       sh0v = __shfl(shl, col16);
      sc1v = __shfl(scl, 16 + col16);  sh1v = __shfl(shl, 16 + col16);
    }

    // ---- normalize + in-wave transpose + gates ----
    #pragma unroll
    for (int cg = 0; cg < 2; ++cg) {
      f32x4 a = cg ? acc1 : acc0;
      const float sc = cg ? sc1v : sc0v, sh = cg ? sh1v : sh0v;
      #pragma unroll
      for (int i = 0; i < 4; ++i)
        waveTr[wid][kg * 4 + i][col16] = a[i] * sc + sh;
      float g0 = waveTr[wid][kg * 4 + d][q * 4 + 0];
      float g1 = waveTr[wid][kg * 4 + d][q * 4 + 1];
      float g2 = waveTr[wid][kg * 4 + d][q * 4 + 2];
      float g3 = waveTr[wid][kg * 4 + d][q * 4 + 3];
      float ig = __builtin_amdgcn_rcpf(1.f + __expf(-g0));
      float fg = __builtin_amdgcn_rcpf(1.f + __expf(-g1));
      float gg = 1.f - 2.f * __builtin_amdgcn_rcpf(__expf(2.f * g2) + 1.f);
      float og = __builtin_amdgcn_rcpf(1.f + __expf(-g3));
      float cn = fg * cst[cg] + ig * gg;
      float hn = og * (1.f - 2.f * __builtin_amdgcn_rcpf(__expf(2.f * cn) + 1.f));
      cst[cg] = cn;
      hnv[cg] = hn;
      hpack[wid][kg * 4 + d][cg * 4 + q] = f2bf(hn);
    }

    if (t < SEQ - 1) {
      // ---- per-wave publish: 16 stores -> OWN vmcnt(0) -> lane0 flag. No barrier. ----
      if (lane < 16) {
        u32x4 hv = *(const u32x4*)&hpack[wid][lane][0];
        unsigned short* hd = hbuf + (pR ^ 1) * (BATCH * HID)
                           + (bid * 128 + wid * 16 + lane) * 8;
        asm volatile("global_store_dwordx4 %0, %1, off sc0 sc1"
                     :: "v"(hd), "v"(hv) : "memory");
      }
      asm volatile("s_waitcnt vmcnt(0)" ::: "memory");   // this wave's stores acked
      if (lane == 0)
        __hip_atomic_store(&flags[(bid * 8 + wid) * 32], (u32)(t + 1),
                           __ATOMIC_RELAXED, __HIP_MEMORY_SCOPE_AGENT);
      // out stores after the flag: off the critical path
      float* po = &out[(size_t)brow * (SEQ * HID) + (size_t)t * HID + bid * FPB];
      po[q]     = hnv[0];
      po[4 + q] = hnv[1];
    } else {
      float* po = &out[(size_t)brow * (SEQ * HID) + (size_t)t * HID + bid * FPB];
      po[q]     = hnv[0];
      po[4 + q] = hnv[1];
      float* ph = &out[(size_t)BATCH * SEQ * HID + (size_t)brow * HID + bid * FPB];
      ph[q] = hnv[0];                 ph[4 + q] = hnv[1];                // hy
      ph[BATCH * HID + q] = cst[0];   ph[BATCH * HID + 4 + q] = cst[1];  // cy
    }
  }
}

extern "C" void kernel_launch(void* const* d_in, const int* in_sizes, int n_in,
                              void* d_out, int out_size, void* d_ws, size_t ws_size,
                              hipStream_t stream) {
  const float* x     = (const float*)d_in[0];
  const float* W     = (const float*)d_in[1];
  // d_in[2] = bias: cancelled by BatchNorm, unused.
  const float* gamma = (const float*)d_in[3];
  const float* beta  = (const float*)d_in[4];
  float* out = (float*)d_out;

  u32* flags = (u32*)d_ws;                                         // 256 @128B = 32 KB
  unsigned short* hbuf = (unsigned short*)((char*)d_ws + 32768);   // 2 x 64 KB

  // reset flags each call (t=0 skips the h read, so hbuf needs no init)
  (void)hipMemsetAsync(d_ws, 0, 32768, stream);
  hipLaunchKernelGGL(bnlstm_kernel, dim3(NBLK), dim3(NTHR), 0, stream,
                     x, W, gamma, beta, out, hbuf, flags);
}